// Round 1
// baseline (127.184 us; speedup 1.0000x reference)
//
#include <hip/hip_runtime.h>

// KnnConvUnit: B=4, N=8192, K=16, C=64, HID=OUT=128.
// out[b,n,:] = (max_k relu(relu(x@W1+b1)@W2+b2)) @ W3 + b3
// x = [f, knn, knn-f]  ->  restructured: h1 = relu(knn@Bm + (f@Aw + b1)),
//   Aw = W1[0:64]-W1[128:192], Bm = W1[64:128]+W1[128:192].
// All GEMMs on v_mfma_f32_16x16x32_f16 with swapped operands
// (weight^T as A-operand -> C cols = data index). Fragment-linear layouts.

#define BB 4
#define NN 8192
#define KK 16
#define CC 64
#define HH 128

typedef _Float16 f16;
typedef _Float16 f16x8 __attribute__((ext_vector_type(8)));
typedef _Float16 f16x4 __attribute__((ext_vector_type(4)));
typedef float f32x4 __attribute__((ext_vector_type(4)));

#define MFMA16(a, b, c) __builtin_amdgcn_mfma_f32_16x16x32_f16(a, b, c, 0, 0, 0)

// ---------------- prep: pack weights into fragment-linear f16 ----------------
// frag fid occupies ws[fid*512 .. fid*512+512) f16; lane l elems at +l*8.
// A-operand frag (out-tile ht, k-tile kt): lane l (g=l>>4, r=l&15), elem j:
//   value = Wmat[k = kt*32 + g*8 + j][h = ht*16 + r]
// regions: Bm: 0..15 (ht*2+kt) | W2: 16..47 (16+ht*4+kt)
//          Aw: 48..63 (48+ht*2+kt) | W3: 64..95 (64+ht*4+kt)
__global__ void prep_pack(const float* __restrict__ W1, const float* __restrict__ W2,
                          const float* __restrict__ W3, f16* __restrict__ ws) {
  int fid = blockIdx.x;
  int l = threadIdx.x;
  int g = l >> 4, r = l & 15;
  f16x8 v;
  if (fid < 16) {                       // Bm = W1b + W1c
    int ht = fid >> 1, kt = fid & 1, h = ht * 16 + r;
#pragma unroll
    for (int j = 0; j < 8; ++j) {
      int k = kt * 32 + g * 8 + j;
      v[j] = (f16)(W1[(64 + k) * HH + h] + W1[(128 + k) * HH + h]);
    }
  } else if (fid < 48) {                // W2
    int t = fid - 16, ht = t >> 2, kt = t & 3, h = ht * 16 + r;
#pragma unroll
    for (int j = 0; j < 8; ++j) {
      int k = kt * 32 + g * 8 + j;
      v[j] = (f16)W2[k * HH + h];
    }
  } else if (fid < 64) {                // Aw = W1a - W1c
    int t = fid - 48, ht = t >> 1, kt = t & 1, h = ht * 16 + r;
#pragma unroll
    for (int j = 0; j < 8; ++j) {
      int k = kt * 32 + g * 8 + j;
      v[j] = (f16)(W1[k * HH + h] - W1[(128 + k) * HH + h]);
    }
  } else {                              // W3
    int t = fid - 64, ht = t >> 2, kt = t & 3, h = ht * 16 + r;
#pragma unroll
    for (int j = 0; j < 8; ++j) {
      int k = kt * 32 + g * 8 + j;
      v[j] = (f16)W3[k * HH + h];
    }
  }
  *(f16x8*)(ws + (size_t)fid * 512 + l * 8) = v;
}

// ---------------- main kernel: 16 points / block, 8 waves ----------------
// LDS: wbuf (Bm+W2 frags, 48KB) | h1buf (8 waves x 2 pts x 4 frags, 64KB)
//      fabuf [16][132] f32 (8448B) | pooled (4 frags, 4KB)   total 127232B
__global__ __launch_bounds__(512, 2) void knn_main(
    const float* __restrict__ f, const int* __restrict__ knn,
    const float* __restrict__ b1, const float* __restrict__ b2,
    const float* __restrict__ b3, const f16* __restrict__ ws,
    float* __restrict__ out) {
  extern __shared__ char smem[];
  f16* wbuf = (f16*)smem;                          // 48*512 f16
  f16* h1buf = wbuf + 48 * 512;                    // 8*2*2048 f16
  float* fabuf = (float*)(h1buf + 8 * 2 * 2048);   // 16*132 f32
  f16* pooled = (f16*)(fabuf + 16 * 132);          // 4*512 f16

  const int tid = threadIdx.x;
  const int wave = tid >> 6, lane = tid & 63;
  const int g = lane >> 4, r = lane & 15;

  const int bid = blockIdx.x;
  const int b = bid >> 9;               // 512 point-groups per batch
  const int n0 = (bid & 511) * 16;
  const float* fb = f + (size_t)b * NN * CC;

  // --- stage Bm+W2 frags into LDS (one-time, reg-staged, conflict-free) ---
  for (int c = tid; c < 48 * 64; c += 512) {
    f16x8 v = *(const f16x8*)(ws + (size_t)c * 8);
    *(f16x8*)(wbuf + (size_t)c * 8) = v;
  }

  // --- fA GEMM: fa[point][hid] = f@Aw + b1; wave handles hid-tile ht=wave ---
  {
    const float* frow = fb + (size_t)(n0 + r) * CC;   // B col = point = r
    f16x8 bf[2];
#pragma unroll
    for (int kt = 0; kt < 2; ++kt) {
      f32x4 a0 = *(const f32x4*)(frow + kt * 32 + g * 8);
      f32x4 a1 = *(const f32x4*)(frow + kt * 32 + g * 8 + 4);
#pragma unroll
      for (int j = 0; j < 4; ++j) { bf[kt][j] = (f16)a0[j]; bf[kt][4 + j] = (f16)a1[j]; }
    }
    f32x4 acc = {0.f, 0.f, 0.f, 0.f};
#pragma unroll
    for (int kt = 0; kt < 2; ++kt) {
      f16x8 af = *(const f16x8*)(ws + (size_t)(48 + wave * 2 + kt) * 512 + lane * 8);
      acc = MFMA16(af, bf[kt], acc);
    }
    // C: col = point = r, row = hid = wave*16 + g*4 + i
    int hid0 = wave * 16 + g * 4;
    f32x4 o;
#pragma unroll
    for (int i = 0; i < 4; ++i) o[i] = acc[i] + b1[hid0 + i];
    *(f32x4*)(fabuf + r * 132 + hid0) = o;
  }

  __syncthreads();

  // --- per-wave: points p0, p0+1 ---
  const int p0 = wave * 2;

  // gather neighbor B-frags: lane: f[idx[p][r]][kt*32 + g*8 + j]
  f16x8 knnf[2][2];
#pragma unroll
  for (int pp = 0; pp < 2; ++pp) {
    int n = n0 + p0 + pp;
    int nidx = knn[((size_t)b * NN + n) * KK + r];
    const float* frow = fb + (size_t)nidx * CC;
#pragma unroll
    for (int kt = 0; kt < 2; ++kt) {
      f32x4 a0 = *(const f32x4*)(frow + kt * 32 + g * 8);
      f32x4 a1 = *(const f32x4*)(frow + kt * 32 + g * 8 + 4);
#pragma unroll
      for (int j = 0; j < 4; ++j) { knnf[pp][kt][j] = (f16)a0[j]; knnf[pp][kt][4 + j] = (f16)a1[j]; }
    }
  }

  // L1: C[hid][nbr] = Bm^T-frags x knn-frags
  f32x4 acc1[2][8];
#pragma unroll
  for (int pp = 0; pp < 2; ++pp)
#pragma unroll
    for (int ht = 0; ht < 8; ++ht) acc1[pp][ht] = (f32x4){0.f, 0.f, 0.f, 0.f};
#pragma unroll
  for (int kt = 0; kt < 2; ++kt) {
#pragma unroll
    for (int ht = 0; ht < 8; ++ht) {
      f16x8 bm = *(const f16x8*)(wbuf + (size_t)(ht * 2 + kt) * 512 + lane * 8);
      acc1[0][ht] = MFMA16(bm, knnf[0][kt], acc1[0][ht]);
      acc1[1][ht] = MFMA16(bm, knnf[1][kt], acc1[1][ht]);
    }
  }
  // epilogue: h1 = relu(acc + fa[p][hid]) -> f16 frag-linear (ds_write_b64)
#pragma unroll
  for (int pp = 0; pp < 2; ++pp) {
    int p = p0 + pp;
    f16* h1p = h1buf + (size_t)(wave * 2 + pp) * 2048;
#pragma unroll
    for (int ht = 0; ht < 8; ++ht) {
      int hid0 = ht * 16 + g * 4;
      f32x4 fa = *(const f32x4*)(fabuf + p * 132 + hid0);
      f16x4 hv;
#pragma unroll
      for (int i = 0; i < 4; ++i) {
        float x = acc1[pp][ht][i] + fa[i];
        hv[i] = (f16)(x > 0.f ? x : 0.f);
      }
      int ktp = hid0 >> 5;
      int slot = (((hid0 >> 3) & 3) << 4) + r;   // lane-slot = g'*16 + nbr
      *(f16x4*)(h1p + ktp * 512 + slot * 8 + (g & 1) * 4) = hv;
    }
  }

  // L2: C[hid2][nbr] = W2^T-frags x h1-frags
  f32x4 acc2[2][8];
#pragma unroll
  for (int pp = 0; pp < 2; ++pp)
#pragma unroll
    for (int h2 = 0; h2 < 8; ++h2) acc2[pp][h2] = (f32x4){0.f, 0.f, 0.f, 0.f};
#pragma unroll
  for (int kt = 0; kt < 4; ++kt) {
    f16x8 h1f[2];
#pragma unroll
    for (int pp = 0; pp < 2; ++pp)
      h1f[pp] = *(const f16x8*)(h1buf + (size_t)(wave * 2 + pp) * 2048 + kt * 512 + lane * 8);
#pragma unroll
    for (int h2 = 0; h2 < 8; ++h2) {
      f16x8 w2f = *(const f16x8*)(wbuf + (size_t)(16 + h2 * 4 + kt) * 512 + lane * 8);
      acc2[0][h2] = MFMA16(w2f, h1f[0], acc2[0][h2]);
      acc2[1][h2] = MFMA16(w2f, h1f[1], acc2[1][h2]);
    }
  }
  // max-pool over nbr (C cols -> lanes r), +b2, relu, write pooled frags
#pragma unroll
  for (int pp = 0; pp < 2; ++pp) {
    int p = p0 + pp;
#pragma unroll
    for (int h2 = 0; h2 < 8; ++h2) {
      int hid0 = h2 * 16 + g * 4;
      f32x4 v = acc2[pp][h2];
#pragma unroll
      for (int m = 1; m < 16; m <<= 1) {
#pragma unroll
        for (int i = 0; i < 4; ++i) v[i] = fmaxf(v[i], __shfl_xor(v[i], m, 64));
      }
      f16x4 pv;
#pragma unroll
      for (int i = 0; i < 4; ++i) {
        float x = v[i] + b2[hid0 + i];
        pv[i] = (f16)(x > 0.f ? x : 0.f);
      }
      if (r == p) {   // one writer column per point
        int ktp = hid0 >> 5;
        int slot = (((hid0 >> 3) & 3) << 4) + p;
        *(f16x4*)(pooled + ktp * 512 + slot * 8 + (g & 1) * 4) = pv;
      }
    }
  }

  __syncthreads();

  // L3: C[od][point] = W3^T-frags x pooled-frags; wave handles od-tile = wave
  {
    f32x4 acc3 = {0.f, 0.f, 0.f, 0.f};
#pragma unroll
    for (int kt = 0; kt < 4; ++kt) {
      f16x8 w3f = *(const f16x8*)(ws + (size_t)(64 + wave * 4 + kt) * 512 + lane * 8);
      f16x8 pf = *(const f16x8*)(pooled + kt * 512 + lane * 8);
      acc3 = MFMA16(w3f, pf, acc3);
    }
    int od0 = wave * 16 + g * 4;
    f32x4 o;
#pragma unroll
    for (int i = 0; i < 4; ++i) o[i] = acc3[i] + b3[od0 + i];
    *(f32x4*)(out + ((size_t)b * NN + n0 + r) * HH + od0) = o;
  }
}

extern "C" void kernel_launch(void* const* d_in, const int* in_sizes, int n_in,
                              void* d_out, int out_size, void* d_ws, size_t ws_size,
                              hipStream_t stream) {
  const float* f = (const float*)d_in[0];
  const int* knn = (const int*)d_in[1];
  const float* W1 = (const float*)d_in[2];
  const float* b1 = (const float*)d_in[3];
  const float* W2 = (const float*)d_in[4];
  const float* b2 = (const float*)d_in[5];
  const float* W3 = (const float*)d_in[6];
  const float* b3 = (const float*)d_in[7];
  float* outp = (float*)d_out;
  f16* wsp = (f16*)d_ws;   // uses 96 frags * 1KB = 96KB of scratch

  (void)hipFuncSetAttribute((const void*)knn_main,
                            hipFuncAttributeMaxDynamicSharedMemorySize, 127232);

  prep_pack<<<96, 64, 0, stream>>>(W1, W2, W3, wsp);
  knn_main<<<(BB * NN) / 16, 512, 127232, stream>>>(f, knn, b1, b2, b3, wsp, outp);
}

// Round 2
// 55.306 us; speedup vs baseline: 2.2997x; 2.2997x over previous
//
#include <hip/hip_runtime.h>

// KnnConvUnit: B=4, N=8192, K=16, C=64, HID=OUT=128.
// out[b,n,:] = (max_k relu(relu(x@W1+b1)@W2+b2)) @ W3 + b3,
//   x = [f, knn, knn-f]  ->  h1 = relu([knn | f] @ [[Bm],[Aw]] + b1)
//   Bm = W1[64:128]+W1[128:192], Aw = W1[0:64]-W1[128:192]  (K=128 folded GEMM)
// All GEMMs: v_mfma_f32_16x16x32_f16 with a shared k-permutation
//   kappa(g,j) = 16*(j>>2) + 4*g + (j&3)   (bijective on [0,32))
// so L1's C layout IS L2's A layout (h1 register-resident), and L2's C
// (rows=nbr) makes max-pool 3 v_max + 2 shfl_xor.

#define BB 4
#define NN 8192
#define KK 16
#define CC 64
#define HH 128

typedef _Float16 f16;
typedef _Float16 f16x8 __attribute__((ext_vector_type(8)));
typedef float f32x4 __attribute__((ext_vector_type(4)));

#define MFMA16(a, b, c) __builtin_amdgcn_mfma_f32_16x16x32_f16(a, b, c, 0, 0, 0)

// ---------------- prep: pack weights, fragment-linear f16, kappa k-order ----
// frag fid = 512 f16 at ws[fid*512]; lane l holds 8 elems at +l*8.
// fid 0..31 : L1 A-frags  (ht=fid>>2, kt=fid&3): kt<2 -> Bm, kt>=2 -> Aw
// fid 32..63: L2 B-frags  (h2t, kt): W2[k][h2t*16+r]
// fid 64..95: L3 A-frags  (ot, kt):  W3[k][ot*16+r]
__global__ void prep_pack(const float* __restrict__ W1, const float* __restrict__ W2,
                          const float* __restrict__ W3, f16* __restrict__ ws) {
  int fid = blockIdx.x;
  int l = threadIdx.x;
  int g = l >> 4, r = l & 15;
  f16x8 v;
#pragma unroll
  for (int j = 0; j < 8; ++j) {
    int kl = 16 * (j >> 2) + 4 * g + (j & 3);   // kappa(g,j)
    float x;
    if (fid < 32) {
      int ht = fid >> 2, kt = fid & 3, h = ht * 16 + r;
      if (kt < 2) {
        int k = kt * 32 + kl;
        x = W1[(64 + k) * HH + h] + W1[(128 + k) * HH + h];   // Bm
      } else {
        int k = (kt - 2) * 32 + kl;
        x = W1[k * HH + h] - W1[(128 + k) * HH + h];          // Aw
      }
    } else if (fid < 64) {
      int t = fid - 32, h2t = t >> 2, kt = t & 3;
      x = W2[(kt * 32 + kl) * HH + h2t * 16 + r];
    } else {
      int t = fid - 64, ot = t >> 2, kt = t & 3;
      x = W3[(kt * 32 + kl) * HH + ot * 16 + r];
    }
    v[j] = (f16)x;
  }
  *(f16x8*)(ws + (size_t)fid * 512 + l * 8) = v;
}

// ---------------- main: 16 points/block, 8 waves, 2 pts/wave ----------------
// LDS: wbuf 64 frags (64KB) + pooled 4 frags (4KB) = 69632 B -> 2 blocks/CU
__global__ __launch_bounds__(512, 4) void knn_main(
    const float* __restrict__ f, const int* __restrict__ knn,
    const float* __restrict__ b1, const float* __restrict__ b2,
    const float* __restrict__ b3, const f16* __restrict__ ws,
    float* __restrict__ out) {
  extern __shared__ char smem[];
  f16* wbuf = (f16*)smem;              // 64*512 f16
  f16* pooled = wbuf + 64 * 512;       // 4*512 f16

  const int tid = threadIdx.x;
  const int wave = tid >> 6, lane = tid & 63;
  const int g = lane >> 4, r = lane & 15;

  // XCD-aware swizzle: 2048 wgs, 8 XCDs -> each XCD owns 256 contiguous wgs
  // (one batch's 2MB f-slab per XCD-pair -> gather is L2-resident)
  const int wg = (blockIdx.x & 7) * 256 + (blockIdx.x >> 3);
  const int b = wg >> 9;
  const int n0 = (wg & 511) * 16;
  const float* fb = f + (size_t)b * NN * CC;
  const int p0 = wave * 2;

  // --- issue knn index loads first (longest dependency chain) ---
  int nidx[2];
#pragma unroll
  for (int pp = 0; pp < 2; ++pp)
    nidx[pp] = knn[(size_t)(b * NN + n0 + p0 + pp) * KK + r];

  // --- stage 64 weight frags into LDS (reg-staged, coalesced, linear) ---
  f16x8 stmp[8];
#pragma unroll
  for (int i = 0; i < 8; ++i)
    stmp[i] = *(const f16x8*)(ws + (size_t)(i * 512 + tid) * 8);
#pragma unroll
  for (int i = 0; i < 8; ++i)
    *(f16x8*)(wbuf + (size_t)(i * 512 + tid) * 8) = stmp[i];

  // --- gather B-frags: kt 0,1 = neighbor row (scattered), kt 2,3 = own row ---
  f16x8 bf[2][4];
#pragma unroll
  for (int pp = 0; pp < 2; ++pp) {
    const float* frow = fb + (size_t)nidx[pp] * CC;
    const float* fown = fb + (size_t)(n0 + p0 + pp) * CC;
#pragma unroll
    for (int kt = 0; kt < 4; ++kt) {
      const float* src = (kt < 2) ? (frow + kt * 32) : (fown + (kt - 2) * 32);
      f32x4 a0 = *(const f32x4*)(src + 4 * g);
      f32x4 a1 = *(const f32x4*)(src + 4 * g + 16);
#pragma unroll
      for (int jl = 0; jl < 4; ++jl) {
        bf[pp][kt][jl] = (f16)a0[jl];
        bf[pp][kt][4 + jl] = (f16)a1[jl];
      }
    }
  }

  __syncthreads();   // wbuf ready

  // --- L1: C[h][nbr] = [Bm;Aw]^T x [knn;f], K=128; h1 -> registers ---
  f16x8 h1f[2][4];
#pragma unroll
  for (int ht = 0; ht < 8; ++ht) {
    f32x4 acc[2] = {{0.f, 0.f, 0.f, 0.f}, {0.f, 0.f, 0.f, 0.f}};
#pragma unroll
    for (int kt = 0; kt < 4; ++kt) {
      f16x8 wfrag = *(const f16x8*)(wbuf + (size_t)(ht * 4 + kt) * 512 + lane * 8);
      acc[0] = MFMA16(wfrag, bf[0][kt], acc[0]);
      acc[1] = MFMA16(wfrag, bf[1][kt], acc[1]);
    }
    f32x4 b1v = *(const f32x4*)(b1 + ht * 16 + g * 4);
#pragma unroll
    for (int pp = 0; pp < 2; ++pp)
#pragma unroll
      for (int i = 0; i < 4; ++i) {
        float x = acc[pp][i] + b1v[i];
        h1f[pp][ht >> 1][(ht & 1) * 4 + i] = (f16)(x > 0.f ? x : 0.f);
      }
  }

  // --- L2: C[nbr][h2] = h1 x W2; pool over nbr = 3 v_max + 2 shfl ---
#pragma unroll
  for (int h2t = 0; h2t < 8; ++h2t) {
    f32x4 acc[2] = {{0.f, 0.f, 0.f, 0.f}, {0.f, 0.f, 0.f, 0.f}};
#pragma unroll
    for (int kt = 0; kt < 4; ++kt) {
      f16x8 w2f = *(const f16x8*)(wbuf + (size_t)(32 + h2t * 4 + kt) * 512 + lane * 8);
      acc[0] = MFMA16(h1f[0][kt], w2f, acc[0]);
      acc[1] = MFMA16(h1f[1][kt], w2f, acc[1]);
    }
    float b2v = b2[h2t * 16 + r];
#pragma unroll
    for (int pp = 0; pp < 2; ++pp) {
      float m = fmaxf(fmaxf(acc[pp][0], acc[pp][1]), fmaxf(acc[pp][2], acc[pp][3]));
      m = fmaxf(m, __shfl_xor(m, 16, 64));
      m = fmaxf(m, __shfl_xor(m, 32, 64));
      float x = m + b2v;
      f16 pv = (f16)(x > 0.f ? x : 0.f);
      if (g == 0) {
        // dest: frag kt3=h2t>>1, lane slot (r>>2)*16 + p, elem (h2t&1)*4 + (r&3)
        pooled[(h2t >> 1) * 512 + ((r >> 2) * 16 + (p0 + pp)) * 8 +
               (h2t & 1) * 4 + (r & 3)] = pv;
      }
    }
  }

  __syncthreads();   // pooled ready (cross-wave)

  // --- L3: C[od][pt] = W3^T x pooled; wave owns od-tile = wave ---
  {
    f32x4 acc3 = {0.f, 0.f, 0.f, 0.f};
#pragma unroll
    for (int kt = 0; kt < 4; ++kt) {
      f16x8 w3f = *(const f16x8*)(ws + (size_t)(64 + wave * 4 + kt) * 512 + lane * 8);
      f16x8 pf = *(const f16x8*)(pooled + kt * 512 + lane * 8);
      acc3 = MFMA16(w3f, pf, acc3);
    }
    f32x4 b3v = *(const f32x4*)(b3 + wave * 16 + g * 4);
    f32x4 o;
#pragma unroll
    for (int i = 0; i < 4; ++i) o[i] = acc3[i] + b3v[i];
    *(f32x4*)(out + ((size_t)b * NN + n0 + r) * HH + wave * 16 + g * 4) = o;
  }
}

extern "C" void kernel_launch(void* const* d_in, const int* in_sizes, int n_in,
                              void* d_out, int out_size, void* d_ws, size_t ws_size,
                              hipStream_t stream) {
  const float* f = (const float*)d_in[0];
  const int* knn = (const int*)d_in[1];
  const float* W1 = (const float*)d_in[2];
  const float* b1 = (const float*)d_in[3];
  const float* W2 = (const float*)d_in[4];
  const float* b2 = (const float*)d_in[5];
  const float* W3 = (const float*)d_in[6];
  const float* b3 = (const float*)d_in[7];
  float* outp = (float*)d_out;
  f16* wsp = (f16*)d_ws;   // 96 frags * 1KB = 96KB scratch

  (void)hipFuncSetAttribute((const void*)knn_main,
                            hipFuncAttributeMaxDynamicSharedMemorySize, 69632);

  prep_pack<<<96, 64, 0, stream>>>(W1, W2, W3, wsp);
  knn_main<<<(BB * NN) / 16, 512, 69632, stream>>>(f, knn, b1, b2, b3, wsp, outp);
}